// Round 2
// 113.999 us; speedup vs baseline: 1.0795x; 1.0795x over previous
//
#include <hip/hip_runtime.h>

#define S_LEN 2048
#define HID   1024
#define NHEAD 16
#define NKVH  4
#define HDIM  64
#define NPROJ 1536   // projection output cols: 1024 Q + 256 K + 256 V
#define QKSTR 1280   // qkv buffer row stride: Q(1024) + K(256); V goes to vT transposed

typedef __bf16 bf16x8 __attribute__((ext_vector_type(8)));
typedef __bf16 bf16x4 __attribute__((ext_vector_type(4)));
typedef float  f32x4  __attribute__((ext_vector_type(4)));

typedef const __attribute__((address_space(1))) void* gas_ptr;
typedef __attribute__((address_space(3))) void*       las_ptr;

// scale = (1/sqrt(1024)) * log2(e): fold softmax scale + base-2 conversion into Q
#define QSCALE 0.04508422f

__device__ __forceinline__ unsigned short f2bf(float f) {
    unsigned u = __builtin_bit_cast(unsigned, f);
    u = u + 0x7FFFu + ((u >> 16) & 1u);   // round-to-nearest-even
    return (unsigned short)(u >> 16);
}

// ---------------- fp32 -> bf16 conversion of x and all weights ----------------
__global__ __launch_bounds__(256) void cvt_all(
    const float* __restrict__ x,  const float* __restrict__ wq,
    const float* __restrict__ wk, const float* __restrict__ wv,
    unsigned short* __restrict__ xbf, unsigned short* __restrict__ wbf)
{
    const long nx  = (long)S_LEN * HID;     // 2097152
    const long nwq = (long)HID * HID;       // 1048576
    const long nwk = (long)256 * HID;       // 262144
    long i = (long)(blockIdx.x * 256 + threadIdx.x) * 4;
    const float* src; unsigned short* dst;
    if (i < nx)                  { src = x  + i;                 dst = xbf + i; }
    else if (i < nx + nwq)       { long j = i - nx;              src = wq + j; dst = wbf + j; }
    else if (i < nx + nwq + nwk) { long j = i - nx - nwq;        src = wk + j; dst = wbf + nwq + j; }
    else                         { long j = i - nx - nwq - nwk;  src = wv + j; dst = wbf + nwq + nwk + j; }
    float4 v = *(const float4*)src;
    ushort4 o; o.x = f2bf(v.x); o.y = f2bf(v.y); o.z = f2bf(v.z); o.w = f2bf(v.w);
    *(ushort4*)dst = o;
}

// ---------------- QKV projection ----------------
// 64x96 tile, grid 16x32 = 512 blocks = 2 blocks/CU (launch_bounds(256,2),
// LDS 40KB/block). With 1 block/CU the per-K-step vmcnt(0)+barrier drain was
// fully exposed; a second resident block (independent barrier domain)
// overlaps its MFMA with this block's drain (m114 mechanism).
__global__ __launch_bounds__(256, 2) void proj_gemm(
    const unsigned short* __restrict__ xbf,
    const unsigned short* __restrict__ wbf,
    unsigned short* __restrict__ qkv,
    unsigned short* __restrict__ vT)
{
    __shared__ unsigned short At[2][64 * 64];
    __shared__ unsigned short Bt[2][96 * 64];
    const int tid = threadIdx.x;
    const int w = tid >> 6, l = tid & 63;
    const int quad = l >> 4, lane16 = l & 15;
    const int m0 = blockIdx.y * 64, n0 = blockIdx.x * 96;
    const int wm = (w & 1) * 32, wn = (w >> 1) * 48;

    const int srow = l >> 3;
    const int scol = ((l & 7) ^ srow) * 8;

    f32x4 acc[2][3] = {};

    #define STAGE(KT, BUF)                                                              \
        do {                                                                            \
            _Pragma("unroll")                                                           \
            for (int c = 0; c < 2; ++c) {                                               \
                const int rbase = w * 16 + c * 8;                                       \
                const unsigned short* ga =                                              \
                    xbf + (long)(m0 + rbase + srow) * HID + (KT) + scol;                \
                __builtin_amdgcn_global_load_lds((gas_ptr)ga,                           \
                    (las_ptr)&At[BUF][rbase * 64], 16, 0, 0);                           \
            }                                                                           \
            _Pragma("unroll")                                                           \
            for (int c = 0; c < 3; ++c) {                                               \
                const int rbase = w * 24 + c * 8;                                       \
                const unsigned short* gb =                                              \
                    wbf + (long)(n0 + rbase + srow) * HID + (KT) + scol;                \
                __builtin_amdgcn_global_load_lds((gas_ptr)gb,                           \
                    (las_ptr)&Bt[BUF][rbase * 64], 16, 0, 0);                           \
            }                                                                           \
        } while (0)

    STAGE(0, 0);

    for (int i = 0; i < 16; ++i) {
        const int cur = i & 1;
        __syncthreads();
        if (i + 1 < 16) STAGE((i + 1) * 64, cur ^ 1);

        #pragma unroll
        for (int ks = 0; ks < 2; ++ks) {
            const int swz = ((ks * 4 + quad) ^ (lane16 & 7)) * 8;
            bf16x8 a[2], b[3];
            #pragma unroll
            for (int mi = 0; mi < 2; ++mi)
                a[mi] = *(const bf16x8*)&At[cur][(wm + mi * 16 + lane16) * 64 + swz];
            #pragma unroll
            for (int ni = 0; ni < 3; ++ni)
                b[ni] = *(const bf16x8*)&Bt[cur][(wn + ni * 16 + lane16) * 64 + swz];
            #pragma unroll
            for (int mi = 0; mi < 2; ++mi)
                #pragma unroll
                for (int ni = 0; ni < 3; ++ni)
                    acc[mi][ni] = __builtin_amdgcn_mfma_f32_16x16x32_bf16(a[mi], b[ni], acc[mi][ni], 0, 0, 0);
        }
    }
    #undef STAGE

    #pragma unroll
    for (int mi = 0; mi < 2; ++mi) {
        const int row = m0 + wm + mi * 16 + quad * 4;
        #pragma unroll
        for (int ni = 0; ni < 3; ++ni) {
            const int col = n0 + wn + ni * 16 + lane16;
            #pragma unroll
            for (int r = 0; r < 4; ++r) {
                const float v = acc[mi][ni][r];
                if (col < 1024)
                    qkv[(long)(row + r) * QKSTR + col] = f2bf(v * QSCALE);
                else if (col < 1280)
                    qkv[(long)(row + r) * QKSTR + col] = f2bf(v);
                else
                    vT[(long)(col - 1280) * S_LEN + (row + r)] = f2bf(v);
            }
        }
    }
}

// ---------------- flash attention (MFMA), causal, GQA rep=4 ----------------
// Transposed QK^T (S^T = K Q^T via swapped MFMA operands; K/Q fragment
// register layouts are identical for A/B roles so the loads are unchanged).
// Each lane holds 16 P-values of ONE q-row (qrow=lane16, kv=t*16+quad*4+r):
// 4 contiguous bf16 per t -> one 8-byte store each.
//
// NaN root-cause fix vs previous attempt: the P-store is now a bf16x4
// (same element family as the bf16x8 PV reads — no TBAA NoAlias edge), the
// inline-asm cvt_pk is gone (plain (__bf16) casts, RNE; per m240 the
// compiler's own conversion is faster anyway), and an explicit compiler
// fence (memory-clobber asm + sched_barrier(0)) sits between P-write and
// P-read so the scheduler cannot hoist the ds_read above the ds_write
// (at kt=0 that read would see uninitialized LDS -> NaN). Hardware-wise the
// per-wave DS pipe is in-order, so forbidding compiler motion suffices;
// the 1-barrier-per-iteration scheme is retained.
#define KSTR 72   // LDS row stride (ushorts): multiple of 8 -> 16B-aligned b128
__global__ __launch_bounds__(256) void attn(
    const unsigned short* __restrict__ qkv,
    const unsigned short* __restrict__ vT,
    float* __restrict__ out)
{
    __shared__ unsigned short Kt[2][64 * KSTR];     // K tile  [kv][d]
    __shared__ unsigned short Vt[2][64 * KSTR];     // V^T tile [d][kv]
    __shared__ unsigned short Pb[4 * 16 * KSTR];    // per-wave P [qrow][kv] (swizzled)

    const int tid = threadIdx.x;
    const int w = tid >> 6, l = tid & 63;
    const int quad = l >> 4, lane16 = l & 15;
    const int bx = blockIdx.x, by = blockIdx.y;
    const int qt = (by & 8) ? (31 - bx) : bx;       // balanced pairing remap
    const int h  = by;
    const int kh = h >> 2;
    const int qcol = h * 64;
    const int kcol = 1024 + kh * 64;

    // Q fragments (m/n=lane&15, k=quad*8+j), Q pre-scaled by proj_gemm
    const long qrow = (long)(qt * 64 + w * 16 + lane16);
    bf16x8 qa0 = *(const bf16x8*)&qkv[qrow * QKSTR + qcol + quad * 8];
    bf16x8 qa1 = *(const bf16x8*)&qkv[qrow * QKSTR + qcol + 32 + quad * 8];

    f32x4 o[4] = {};
    float rsum[4] = {0.f, 0.f, 0.f, 0.f};

    unsigned short* pw = &Pb[w * 16 * KSTR];

    // staging coords: 256 thr x 16 ushorts cover each 64x64 tile
    const int sr = tid >> 2, ss = tid & 3;
    const long vrow = (long)(kh * 64 + sr) * S_LEN;

    // prologue: prefetch tile 0 into registers
    bf16x8 kr0, kr1, vr0, vr1;
    {
        const long gk = (long)sr * QKSTR + kcol + ss * 16;
        kr0 = *(const bf16x8*)&qkv[gk];
        kr1 = *(const bf16x8*)&qkv[gk + 8];
        const long gv = vrow + ss * 16;
        vr0 = *(const bf16x8*)&vT[gv];
        vr1 = *(const bf16x8*)&vT[gv + 8];
    }

    for (int kt = 0; kt <= qt; ++kt) {
        const int cur = kt & 1;
        // (A) store prefetched tile into buf[cur]; prefetch next into regs
        *(bf16x8*)&Kt[cur][sr * KSTR + ss * 16]     = kr0;
        *(bf16x8*)&Kt[cur][sr * KSTR + ss * 16 + 8] = kr1;
        *(bf16x8*)&Vt[cur][sr * KSTR + ss * 16]     = vr0;
        *(bf16x8*)&Vt[cur][sr * KSTR + ss * 16 + 8] = vr1;
        if (kt < qt) {                        // uniform branch
            const long gk = (long)((kt + 1) * 64 + sr) * QKSTR + kcol + ss * 16;
            kr0 = *(const bf16x8*)&qkv[gk];
            kr1 = *(const bf16x8*)&qkv[gk + 8];
            const long gv = vrow + (kt + 1) * 64 + ss * 16;
            vr0 = *(const bf16x8*)&vT[gv];
            vr1 = *(const bf16x8*)&vT[gv + 8];
        }
        __syncthreads();                      // (B) staging[cur] visible

        // S^T = K Q^T  (64 kv x 16 q-rows); A = K (m=kv), B = Q (n=qrow)
        // C layout per tile t: row = kv = t*16 + quad*4 + r, col = qrow = lane16
        f32x4 sacc[4] = {};
        #pragma unroll
        for (int t = 0; t < 4; ++t) {
            bf16x8 kb0 = *(const bf16x8*)&Kt[cur][(t * 16 + lane16) * KSTR + quad * 8];
            bf16x8 kb1 = *(const bf16x8*)&Kt[cur][(t * 16 + lane16) * KSTR + 32 + quad * 8];
            sacc[t] = __builtin_amdgcn_mfma_f32_16x16x32_bf16(kb0, qa0, sacc[t], 0, 0, 0);
            sacc[t] = __builtin_amdgcn_mfma_f32_16x16x32_bf16(kb1, qa1, sacc[t], 0, 0, 0);
        }

        // causal mask on diagonal tile: kv > qrow  (both local to this 64-block)
        if (kt == qt) {
            #pragma unroll
            for (int t = 0; t < 4; ++t) {
                const int kvw = t * 16 + quad * 4;
                #pragma unroll
                for (int r = 0; r < 4; ++r)
                    if (kvw + r > w * 16 + lane16) sacc[t][r] = -3.0e38f;
            }
        }

        // p = exp2(s) directly (scores bounded; masked -> +0). Lane's 4 values
        // per t are contiguous kv of q-row lane16: one bf16x4 store per t.
        #pragma unroll
        for (int t = 0; t < 4; ++t) {
            const float p0 = __builtin_amdgcn_exp2f(sacc[t][0]);
            const float p1 = __builtin_amdgcn_exp2f(sacc[t][1]);
            const float p2 = __builtin_amdgcn_exp2f(sacc[t][2]);
            const float p3 = __builtin_amdgcn_exp2f(sacc[t][3]);
            rsum[t] += (p0 + p1) + (p2 + p3);
            bf16x4 pk;
            pk[0] = (__bf16)p0; pk[1] = (__bf16)p1;
            pk[2] = (__bf16)p2; pk[3] = (__bf16)p3;
            *(bf16x4*)&pw[lane16 * KSTR + ((t * 16 + quad * 4) ^ ((lane16 & 12) << 1))] = pk;
        }

        // Compiler fence: forbid hoisting the PV ds_reads above the P ds_writes
        // (per-wave DS pipe is in-order in HW; only compiler motion is unsafe).
        asm volatile("" ::: "memory");
        __builtin_amdgcn_sched_barrier(0);

        // O += P V   (A = P [m=qrow][k=kv], B = V^T [n=d][k=kv])
        #pragma unroll
        for (int ks = 0; ks < 2; ++ks) {
            bf16x8 pa = *(const bf16x8*)&pw[lane16 * KSTR + ((ks * 32 + quad * 8) ^ ((lane16 & 12) << 1))];
            #pragma unroll
            for (int t = 0; t < 4; ++t) {
                bf16x8 vb = *(const bf16x8*)&Vt[cur][(t * 16 + lane16) * KSTR + ks * 32 + quad * 8];
                o[t] = __builtin_amdgcn_mfma_f32_16x16x32_bf16(pa, vb, o[t], 0, 0, 0);
            }
        }
    }

    // row-sum: lane's partials cover a full q-row chunk (qrow=lane16);
    // sum the 4 quad-chunks (lanes l^16, l^32), then broadcast 1/sum to the
    // O-accumulator layout (row = quad*4 + r).
    float total = (rsum[0] + rsum[1]) + (rsum[2] + rsum[3]);
    total += __shfl_xor(total, 16);
    total += __shfl_xor(total, 32);
    const float invt = 1.0f / total;
    float inv[4];
    #pragma unroll
    for (int r = 0; r < 4; ++r)
        inv[r] = __shfl(invt, quad * 4 + r);

    const int orow = qt * 64 + w * 16 + quad * 4;
    #pragma unroll
    for (int t = 0; t < 4; ++t) {
        const int col = h * 64 + t * 16 + lane16;
        #pragma unroll
        for (int r = 0; r < 4; ++r)
            out[(long)(orow + r) * (NHEAD * HDIM) + col] = o[t][r] * inv[r];
    }
}

extern "C" void kernel_launch(void* const* d_in, const int* in_sizes, int n_in,
                              void* d_out, int out_size, void* d_ws, size_t ws_size,
                              hipStream_t stream) {
    const float* x  = (const float*)d_in[0];
    const float* wq = (const float*)d_in[1];
    const float* wk = (const float*)d_in[2];
    const float* wv = (const float*)d_in[3];
    float* out = (float*)d_out;

    unsigned short* xbf = (unsigned short*)d_ws;                 // 2048*1024
    unsigned short* wbf = xbf + (size_t)S_LEN * HID;             // 1536*1024
    unsigned short* qkv = wbf + (size_t)NPROJ * HID;             // 2048*1280 (Q+K)
    unsigned short* vT  = qkv + (size_t)S_LEN * QKSTR;           // 256*2048  (V^T)

    cvt_all<<<dim3(3584), dim3(256), 0, stream>>>(x, wq, wk, wv, xbf, wbf);
    proj_gemm<<<dim3(16, 32), dim3(256), 0, stream>>>(xbf, wbf, qkv, vT);
    attn<<<dim3(32, 16), dim3(256), 0, stream>>>(qkv, vT, out);
}